// Round 3
// baseline (2365.535 us; speedup 1.0000x reference)
//
#include <hip/hip_runtime.h>
#include <hip/hip_bf16.h>
#include <cstdint>
#include <cstddef>

typedef short bf16x8 __attribute__((ext_vector_type(8)));
typedef float f32x4 __attribute__((ext_vector_type(4)));
typedef unsigned short u16x4v __attribute__((ext_vector_type(4)));

__device__ __forceinline__ float bf2f(unsigned short u) {
  union { unsigned int u; float f; } v; v.u = ((unsigned int)u) << 16; return v.f;
}
__device__ __forceinline__ unsigned short f2bf(float f) {
  union { float f; unsigned int u; } v; v.f = f;
  unsigned int r = v.u + 0x7fffu + ((v.u >> 16) & 1u);
  return (unsigned short)(r >> 16);
}
__device__ __forceinline__ int pack2(float a, float b) {
  return (int)f2bf(a) | ((int)f2bf(b) << 16);
}

// ---------------- all-weight transpose+convert in ONE kernel ----------------
struct WPack {
  const float* in[6];
  unsigned short* out[6];
  int K[6], Ncol[6];
  int start[7];
};
__global__ __launch_bounds__(256) void convert_all(WPack p) {
  int idx = blockIdx.x * 256 + threadIdx.x;
  #pragma unroll
  for (int s = 0; s < 6; ++s) {
    if (idx >= p.start[s] && idx < p.start[s + 1]) {
      int lidx = idx - p.start[s];
      int k = lidx / p.Ncol[s], n = lidx % p.Ncol[s];
      p.out[s][n * p.K[s] + k] = f2bf(p.in[s][lidx]);
    }
  }
}

// ---------------- GEMM: C[M,Ncol] = A[M,K] @ Wt[Ncol,K]^T (f32 acc, bf16 out)
template<int BN, int WAVES_M, int WAVES_N, bool AF32>
__global__ __launch_bounds__(256) void gemm_dual(
    const void* __restrict__ Av,
    const unsigned short* __restrict__ BtL, const unsigned short* __restrict__ BtR,
    unsigned short* __restrict__ outL, unsigned short* __restrict__ outR,
    int M, int K, int Ncol) {
  constexpr int BM = 128, BK = 64;
  constexpr int WTM = BM / WAVES_M, WTN = BN / WAVES_N;
  constexpr int MR = WTM / 16, NR = WTN / 16;
  const unsigned short* __restrict__ Bt = blockIdx.z ? BtR : BtL;
  unsigned short* __restrict__ outp = blockIdx.z ? outR : outL;

  __shared__ alignas(16) unsigned short lAt[BM * BK];
  __shared__ alignas(16) unsigned short lBt[BN * BK];

  int t = threadIdx.x;
  int lane = t & 63, wid = t >> 6;
  int wm = wid / WAVES_N, wn = wid % WAVES_N;
  int rowBase = blockIdx.x * BM;
  int colBase = blockIdx.y * BN;

  f32x4 acc[MR][NR] = {};

  for (int k0 = 0; k0 < K; k0 += BK) {
    #pragma unroll
    for (int p = 0; p < (BM * 8) / 256; ++p) {
      int lin = p * 256 + t;
      int row = lin >> 3, c = lin & 7;
      int gr = rowBase + row;
      int4 w = make_int4(0, 0, 0, 0);
      if constexpr (AF32) {
        const float* A = (const float*)Av;
        if (gr < M) {
          const float* ap = A + (size_t)gr * K + k0 + c * 8;
          f32x4 f0 = *reinterpret_cast<const f32x4*>(ap);
          f32x4 f1 = *reinterpret_cast<const f32x4*>(ap + 4);
          w.x = pack2(f0[0], f0[1]); w.y = pack2(f0[2], f0[3]);
          w.z = pack2(f1[0], f1[1]); w.w = pack2(f1[2], f1[3]);
        }
      } else {
        const unsigned short* A = (const unsigned short*)Av;
        if (gr < M) w = *reinterpret_cast<const int4*>(A + (size_t)gr * K + k0 + c * 8);
      }
      *reinterpret_cast<int4*>(&lAt[row * 64 + ((c ^ (row & 7)) * 8)]) = w;
    }
    #pragma unroll
    for (int p = 0; p < (BN * 8) / 256; ++p) {
      int lin = p * 256 + t;
      int row = lin >> 3, c = lin & 7;
      int4 v = *reinterpret_cast<const int4*>(Bt + (size_t)(colBase + row) * K + k0 + c * 8);
      *reinterpret_cast<int4*>(&lBt[row * 64 + ((c ^ (row & 7)) * 8)]) = v;
    }
    __syncthreads();
    #pragma unroll
    for (int kk = 0; kk < 2; ++kk) {
      bf16x8 af[MR], bfr[NR];
      int cidx = kk * 4 + (lane >> 4);
      #pragma unroll
      for (int mi = 0; mi < MR; ++mi) {
        int row = wm * WTM + mi * 16 + (lane & 15);
        af[mi] = *reinterpret_cast<const bf16x8*>(&lAt[row * 64 + ((cidx ^ (row & 7)) * 8)]);
      }
      #pragma unroll
      for (int ni = 0; ni < NR; ++ni) {
        int row = wn * WTN + ni * 16 + (lane & 15);
        bfr[ni] = *reinterpret_cast<const bf16x8*>(&lBt[row * 64 + ((cidx ^ (row & 7)) * 8)]);
      }
      #pragma unroll
      for (int mi = 0; mi < MR; ++mi)
        #pragma unroll
        for (int ni = 0; ni < NR; ++ni)
          acc[mi][ni] = __builtin_amdgcn_mfma_f32_16x16x32_bf16(af[mi], bfr[ni], acc[mi][ni], 0, 0, 0);
    }
    __syncthreads();
  }
  #pragma unroll
  for (int mi = 0; mi < MR; ++mi)
    #pragma unroll
    for (int ni = 0; ni < NR; ++ni) {
      int col = colBase + wn * WTN + ni * 16 + (lane & 15);
      #pragma unroll
      for (int r = 0; r < 4; ++r) {
        int row = rowBase + wm * WTM + mi * 16 + (lane >> 4) * 4 + r;
        if (row < M) outp[(size_t)row * Ncol + col] = f2bf(acc[mi][ni][r]);
      }
    }
}

// ---------------- CSR build ----------------
__global__ __launch_bounds__(256) void hist_kernel(const int* __restrict__ dst, int* __restrict__ counts, int E) {
  int e = blockIdx.x * 256 + threadIdx.x;
  if (e < E) atomicAdd(&counts[dst[e]], 1);
}

__global__ __launch_bounds__(256) void scan_block(const int* __restrict__ in, int* __restrict__ out,
                                                  int* __restrict__ sums, int n) {
  int i = blockIdx.x * 256 + threadIdx.x;
  int lane = threadIdx.x & 63, wid = threadIdx.x >> 6;
  int v = (i < n) ? in[i] : 0;
  int s = v;
  #pragma unroll
  for (int d = 1; d < 64; d <<= 1) { int tt = __shfl_up(s, d); if (lane >= d) s += tt; }
  __shared__ int wsum[4];
  if (lane == 63) wsum[wid] = s;
  __syncthreads();
  int off = 0;
  for (int w = 0; w < wid; ++w) off += wsum[w];
  if (i < n) out[i] = off + s - v;  // exclusive
  if (threadIdx.x == 255) sums[blockIdx.x] = off + s;
}

__global__ __launch_bounds__(256) void scan_add(int* __restrict__ rs, const int* __restrict__ boffs,
                                                int* __restrict__ cursor, int n, int E) {
  int i = blockIdx.x * 256 + threadIdx.x;
  if (i < n) {
    int v = rs[i] + boffs[blockIdx.x];
    rs[i] = v;
    cursor[i] = v;
  }
  if (i == 0) rs[n] = E;
}

__global__ __launch_bounds__(256) void scatter_kernel(const int* __restrict__ src, const int* __restrict__ dst,
                                                      int* __restrict__ cursor, int* __restrict__ csr, int E) {
  int e = blockIdx.x * 256 + threadIdx.x;
  if (e < E) {
    int p = atomicAdd(&cursor[dst[e]], 1);
    csr[p] = src[e];
  }
}

// ---------------- edge aggregation helpers ----------------
template<int VEC>
__device__ __forceinline__ void load_row(const unsigned short* __restrict__ base,
                                         int s, int lane, float* v) {
  if constexpr (VEC == 4) {
    u16x4v r = *reinterpret_cast<const u16x4v*>(base + (size_t)s * 256 + lane * 4);
    #pragma unroll
    for (int j = 0; j < 4; ++j) v[j] = bf2f(r[j]);
  } else {
    v[0] = bf2f(base[(size_t)s * 64 + lane]);
  }
}

template<int VEC, int GROUP>
__device__ __forceinline__ float edge_score(const float* xv, const float* xrv, const float* attv) {
  float p = 0.f;
  #pragma unroll
  for (int j = 0; j < VEC; ++j) {
    float tv = xv[j] + xrv[j];
    tv = fmaxf(tv, 0.2f * tv);     // leaky_relu slope 0.2
    p = fmaf(tv, attv[j], p);
  }
  #pragma unroll
  for (int msk = 1; msk < GROUP; msk <<= 1) p += __shfl_xor(p, msk);
  return p;
}

// one wave per dst node, persistent waves + work stealing, online softmax with
// deferred-max rescale (threshold 8), 2-edge unroll for memory parallelism.
template<int H, bool SELF, bool RELU>
__global__ __launch_bounds__(256) void edge_agg(
    const unsigned short* __restrict__ xl, const unsigned short* __restrict__ xr,
    const float* __restrict__ att, const float* __restrict__ bias,
    const int* __restrict__ rowstart, const int* __restrict__ csr,
    unsigned short* __restrict__ out, int* __restrict__ ctr, int N) {
  constexpr int F = H * 64;
  constexpr int VEC = F / 64;
  constexpr int GROUP = 64 / H;
  int lane = threadIdx.x & 63;

  float attv[VEC];
  #pragma unroll
  for (int j = 0; j < VEC; ++j) attv[j] = att[lane * VEC + j];

  while (true) {
    int node;
    if (lane == 0) node = atomicAdd(ctr, 1);
    node = __shfl(node, 0);
    if (node >= N) return;

    float xrv[VEC];
    load_row<VEC>(xr, node, lane, xrv);

    int s0 = rowstart[node], s1 = rowstart[node + 1];
    int end = s1 + (SELF ? 1 : 0);

    float m = 0.f, l = 0.f;
    float acc[VEC];
    #pragma unroll
    for (int j = 0; j < VEC; ++j) acc[j] = 0.f;

    int i = s0;
    if (i < end) {           // first edge: m := its score, w == 1
      int s = (i < s1) ? csr[i] : node;
      float xv[VEC];
      load_row<VEC>(xl, s, lane, xv);
      m = edge_score<VEC, GROUP>(xv, xrv, attv);
      l = 1.f;
      #pragma unroll
      for (int j = 0; j < VEC; ++j) acc[j] = xv[j];
      ++i;
    }
    for (; i + 2 <= end; i += 2) {
      int sA = (i < s1) ? csr[i] : node;
      int sB = (i + 1 < s1) ? csr[i + 1] : node;
      float xa[VEC], xb[VEC];
      load_row<VEC>(xl, sA, lane, xa);
      load_row<VEC>(xl, sB, lane, xb);
      float pA = edge_score<VEC, GROUP>(xa, xrv, attv);
      float pB = edge_score<VEC, GROUP>(xb, xrv, attv);
      float mx = fmaxf(pA, pB);
      if (__any(mx > m + 8.f)) {          // rare rescale
        float mn = fmaxf(m, mx);
        float sc = __expf(m - mn);
        l *= sc;
        #pragma unroll
        for (int j = 0; j < VEC; ++j) acc[j] *= sc;
        m = mn;
      }
      float wA = __expf(pA - m), wB = __expf(pB - m);
      l += wA + wB;
      #pragma unroll
      for (int j = 0; j < VEC; ++j) acc[j] = fmaf(wA, xa[j], fmaf(wB, xb[j], acc[j]));
    }
    if (i < end) {
      int s = (i < s1) ? csr[i] : node;
      float xv[VEC];
      load_row<VEC>(xl, s, lane, xv);
      float p = edge_score<VEC, GROUP>(xv, xrv, attv);
      if (__any(p > m + 8.f)) {
        float mn = fmaxf(m, p);
        float sc = __expf(m - mn);
        l *= sc;
        #pragma unroll
        for (int j = 0; j < VEC; ++j) acc[j] *= sc;
        m = mn;
      }
      float w = __expf(p - m);
      l += w;
      #pragma unroll
      for (int j = 0; j < VEC; ++j) acc[j] = fmaf(w, xv[j], acc[j]);
    }

    float rec = 1.f / (l + 1e-16f);
    if constexpr (VEC == 4) {
      u16x4v w4;
      #pragma unroll
      for (int j = 0; j < 4; ++j) {
        float o = fmaf(acc[j], rec, bias[lane * 4 + j]);
        if (RELU) o = fmaxf(o, 0.f);
        w4[j] = f2bf(o);
      }
      *reinterpret_cast<u16x4v*>(out + (size_t)node * 256 + lane * 4) = w4;
    } else {
      float o = fmaf(acc[0], rec, bias[lane]);
      if (RELU) o = fmaxf(o, 0.f);
      out[(size_t)node * 64 + lane] = f2bf(o);
    }
  }
}

// ---------------- global mean pool (atomic) ----------------
__global__ __launch_bounds__(256) void pool_kernel(const unsigned short* __restrict__ h,
                                                   const int* __restrict__ batch,
                                                   float* __restrict__ gsum, int* __restrict__ gcnt, int N) {
  int wave = threadIdx.x >> 6, lane = threadIdx.x & 63;
  int node = blockIdx.x * 4 + wave;
  if (node >= N) return;
  int b = batch[node];
  atomicAdd(&gsum[(size_t)b * 64 + lane], bf2f(h[(size_t)node * 64 + lane]));
  if (lane == 0) atomicAdd(&gcnt[b], 1);
}

// ---------------- MLP head + softmax: one wave per graph (all f32) ----------------
__global__ __launch_bounds__(256) void mlp_kernel(
    const float* __restrict__ gsum, const int* __restrict__ gcnt,
    const float* __restrict__ w1, const float* __restrict__ b1,
    const float* __restrict__ w2, const float* __restrict__ b2,
    const float* __restrict__ w3, const float* __restrict__ b3,
    float* __restrict__ out, int G) {
  int wave = threadIdx.x >> 6, lane = threadIdx.x & 63;
  int r = blockIdx.x * 4 + wave;
  bool ok = r < G;
  __shared__ float sh[4][64];
  float xv = 0.f;
  if (ok) {
    float cnt = fmaxf((float)gcnt[r], 1.0f);
    xv = gsum[(size_t)r * 64 + lane] / cnt;
  }
  sh[wave][lane] = xv;
  __syncthreads();
  float h1 = b1[lane];
  for (int k = 0; k < 64; ++k) h1 = fmaf(sh[wave][k], w1[k * 64 + lane], h1);
  h1 = fmaxf(h1, 0.f);
  __syncthreads();
  sh[wave][lane] = h1;
  __syncthreads();
  float h2 = b2[lane];
  for (int k = 0; k < 64; ++k) h2 = fmaf(sh[wave][k], w2[k * 64 + lane], h2);
  h2 = fmaxf(h2, 0.f);
  __syncthreads();
  sh[wave][lane] = h2;
  __syncthreads();
  float lg = -INFINITY;
  if (lane < 12) {
    lg = b3[lane];
    for (int k = 0; k < 64; ++k) lg = fmaf(sh[wave][k], w3[k * 12 + lane], lg);
  }
  float mx = lg;
  #pragma unroll
  for (int msk = 1; msk < 64; msk <<= 1) mx = fmaxf(mx, __shfl_xor(mx, msk));
  float ex = (lane < 12) ? __expf(lg - mx) : 0.f;
  float sm = ex;
  #pragma unroll
  for (int msk = 1; msk < 64; msk <<= 1) sm += __shfl_xor(sm, msk);
  if (ok && lane < 12) out[(size_t)r * 12 + lane] = ex / sm;
}

// ---------------- host ----------------
extern "C" void kernel_launch(void* const* d_in, const int* in_sizes, int n_in,
                              void* d_out, int out_size, void* d_ws, size_t ws_size,
                              hipStream_t stream) {
  const float* x    = (const float*)d_in[0];
  const int* edge   = (const int*)d_in[1];
  const int* batch  = (const int*)d_in[2];
  const float* W1l  = (const float*)d_in[3];
  const float* W1r  = (const float*)d_in[4];
  const float* a1   = (const float*)d_in[5];
  const float* b1   = (const float*)d_in[6];
  const float* W2l  = (const float*)d_in[7];
  const float* W2r  = (const float*)d_in[8];
  const float* a2   = (const float*)d_in[9];
  const float* b2   = (const float*)d_in[10];
  const float* W3l  = (const float*)d_in[11];
  const float* W3r  = (const float*)d_in[12];
  const float* a3   = (const float*)d_in[13];
  const float* b3   = (const float*)d_in[14];
  const float* lw1  = (const float*)d_in[15];
  const float* lb1  = (const float*)d_in[16];
  const float* lw2  = (const float*)d_in[17];
  const float* lb2  = (const float*)d_in[18];
  const float* lw3  = (const float*)d_in[19];
  const float* lb3  = (const float*)d_in[20];

  const int E = in_sizes[1] / 2;
  const int N = in_sizes[2];
  const int F0 = in_sizes[0] / N;   // 128
  const int G = out_size / 12;      // 512
  const int* src = edge;
  const int* dst = edge + E;

  // workspace carve (256B aligned)
  char* p = (char*)d_ws;
  auto alloc = [&](size_t bytes) { char* q = p; p += (bytes + 255) & ~(size_t)255; return q; };
  unsigned short* bufA = (unsigned short*)alloc((size_t)N * 256 * 2);
  unsigned short* bufB = (unsigned short*)alloc((size_t)N * 256 * 2);
  unsigned short* bufH = (unsigned short*)alloc((size_t)N * 256 * 2);
  unsigned short* Wt1L = (unsigned short*)alloc(128 * 256 * 2);
  unsigned short* Wt1R = (unsigned short*)alloc(128 * 256 * 2);
  unsigned short* Wt2L = (unsigned short*)alloc(256 * 256 * 2);
  unsigned short* Wt2R = (unsigned short*)alloc(256 * 256 * 2);
  unsigned short* Wt3L = (unsigned short*)alloc(256 * 64 * 2);
  unsigned short* Wt3R = (unsigned short*)alloc(256 * 64 * 2);
  int* ctrs     = (int*)alloc(256);              // 3 steal counters (zeroed w/ counts)
  int* counts   = (int*)alloc((size_t)N * 4);    // contiguous with ctrs
  int* rowstart = (int*)alloc((size_t)(N + 1) * 4);
  int* cursor   = (int*)alloc((size_t)N * 4);
  int* bsums    = (int*)alloc(4096 * 4);
  int* boffs    = (int*)alloc(4096 * 4);
  int* dummy    = (int*)alloc(64 * 4);
  int* csr      = (int*)alloc((size_t)E * 4);
  float* gsum   = (float*)alloc((size_t)G * 64 * 4);  // contiguous with gcnt
  int* gcnt     = (int*)alloc((size_t)G * 4);

  // ---- CSR by dst (built once, reused by all convs); zero ctrs+counts in one go ----
  hipMemsetAsync(ctrs, 0, 256 + (((size_t)N * 4 + 255) & ~(size_t)255), stream);
  hist_kernel<<<(E + 255) / 256, 256, 0, stream>>>(dst, counts, E);
  int nb = (N + 255) / 256;
  scan_block<<<nb, 256, 0, stream>>>(counts, rowstart, bsums, N);
  scan_block<<<1, 256, 0, stream>>>(bsums, boffs, dummy, nb);
  scan_add<<<nb, 256, 0, stream>>>(rowstart, boffs, cursor, N, E);
  scatter_kernel<<<(E + 255) / 256, 256, 0, stream>>>(src, dst, cursor, csr, E);

  // ---- all weight transposes in one launch ----
  {
    WPack wp;
    const float* ins[6] = {W1l, W1r, W2l, W2r, W3l, W3r};
    unsigned short* outs[6] = {Wt1L, Wt1R, Wt2L, Wt2R, Wt3L, Wt3R};
    int Ks[6] = {F0, F0, 256, 256, 256, 256};
    int Ns[6] = {256, 256, 256, 256, 64, 64};
    int acc0 = 0;
    for (int s = 0; s < 6; ++s) {
      wp.in[s] = ins[s]; wp.out[s] = outs[s]; wp.K[s] = Ks[s]; wp.Ncol[s] = Ns[s];
      wp.start[s] = acc0; acc0 += Ks[s] * Ns[s];
    }
    wp.start[6] = acc0;
    convert_all<<<(acc0 + 255) / 256, 256, 0, stream>>>(wp);
  }

  int gx = (N + 127) / 128;

  // ---- conv1: K=F0(128), Ncol=256, no self loops, relu; A = x (f32) ----
  gemm_dual<128, 2, 2, true><<<dim3(gx, 2, 2), 256, 0, stream>>>(x, Wt1L, Wt1R, bufA, bufB, N, F0, 256);
  edge_agg<4, false, true><<<2048, 256, 0, stream>>>(bufA, bufB, a1, b1, rowstart, csr, bufH, ctrs + 0, N);

  // ---- conv2: K=256, Ncol=256, self loops, relu; A = bufH (bf16) ----
  gemm_dual<128, 2, 2, false><<<dim3(gx, 2, 2), 256, 0, stream>>>(bufH, Wt2L, Wt2R, bufA, bufB, N, 256, 256);
  edge_agg<4, true, true><<<2048, 256, 0, stream>>>(bufA, bufB, a2, b2, rowstart, csr, bufH, ctrs + 1, N);

  // ---- conv3: K=256, Ncol=64, self loops, no relu; A = bufH (bf16) ----
  gemm_dual<64, 4, 1, false><<<dim3(gx, 1, 2), 256, 0, stream>>>(bufH, Wt3L, Wt3R, bufA, bufB, N, 256, 64);
  edge_agg<1, true, false><<<2048, 256, 0, stream>>>(bufA, bufB, a3, b3, rowstart, csr, bufH, ctrs + 2, N);

  // ---- global mean pool (gsum+gcnt zeroed in one memset; contiguous) ----
  hipMemsetAsync(gsum, 0, (size_t)G * 64 * 4 + (size_t)G * 4, stream);
  pool_kernel<<<(N + 3) / 4, 256, 0, stream>>>(bufH, batch, gsum, gcnt, N);

  // ---- MLP head + softmax ----
  mlp_kernel<<<(G + 3) / 4, 256, 0, stream>>>(gsum, gcnt, lw1, lb1, lw2, lb2, lw3, lb3,
                                              (float*)d_out, G);
}

// Round 4
// 594.521 us; speedup vs baseline: 3.9789x; 3.9789x over previous
//
#include <hip/hip_runtime.h>
#include <hip/hip_bf16.h>
#include <cstdint>
#include <cstddef>

typedef short bf16x8 __attribute__((ext_vector_type(8)));
typedef float f32x4 __attribute__((ext_vector_type(4)));
typedef unsigned short u16x4v __attribute__((ext_vector_type(4)));

__device__ __forceinline__ float bf2f(unsigned short u) {
  union { unsigned int u; float f; } v; v.u = ((unsigned int)u) << 16; return v.f;
}
__device__ __forceinline__ unsigned short f2bf(float f) {
  union { float f; unsigned int u; } v; v.f = f;
  unsigned int r = v.u + 0x7fffu + ((v.u >> 16) & 1u);
  return (unsigned short)(r >> 16);
}
__device__ __forceinline__ int pack2(float a, float b) {
  return (int)f2bf(a) | ((int)f2bf(b) << 16);
}

// ---------------- all-weight transpose+convert in ONE kernel ----------------
struct WPack {
  const float* in[6];
  unsigned short* out[6];
  int K[6], Ncol[6];
  int start[7];
};
__global__ __launch_bounds__(256) void convert_all(WPack p) {
  int idx = blockIdx.x * 256 + threadIdx.x;
  #pragma unroll
  for (int s = 0; s < 6; ++s) {
    if (idx >= p.start[s] && idx < p.start[s + 1]) {
      int lidx = idx - p.start[s];
      int k = lidx / p.Ncol[s], n = lidx % p.Ncol[s];
      p.out[s][n * p.K[s] + k] = f2bf(p.in[s][lidx]);
    }
  }
}

// ---------------- GEMM: C[M,Ncol] = A[M,K] @ Wt[Ncol,K]^T (f32 acc, bf16 out)
template<int BN, int WAVES_M, int WAVES_N, bool AF32>
__global__ __launch_bounds__(256) void gemm_dual(
    const void* __restrict__ Av,
    const unsigned short* __restrict__ BtL, const unsigned short* __restrict__ BtR,
    unsigned short* __restrict__ outL, unsigned short* __restrict__ outR,
    int M, int K, int Ncol) {
  constexpr int BM = 128, BK = 64;
  constexpr int WTM = BM / WAVES_M, WTN = BN / WAVES_N;
  constexpr int MR = WTM / 16, NR = WTN / 16;
  const unsigned short* __restrict__ Bt = blockIdx.z ? BtR : BtL;
  unsigned short* __restrict__ outp = blockIdx.z ? outR : outL;

  __shared__ alignas(16) unsigned short lAt[BM * BK];
  __shared__ alignas(16) unsigned short lBt[BN * BK];

  int t = threadIdx.x;
  int lane = t & 63, wid = t >> 6;
  int wm = wid / WAVES_N, wn = wid % WAVES_N;
  int rowBase = blockIdx.x * BM;
  int colBase = blockIdx.y * BN;

  f32x4 acc[MR][NR] = {};

  for (int k0 = 0; k0 < K; k0 += BK) {
    #pragma unroll
    for (int p = 0; p < (BM * 8) / 256; ++p) {
      int lin = p * 256 + t;
      int row = lin >> 3, c = lin & 7;
      int gr = rowBase + row;
      int4 w = make_int4(0, 0, 0, 0);
      if constexpr (AF32) {
        const float* A = (const float*)Av;
        if (gr < M) {
          const float* ap = A + (size_t)gr * K + k0 + c * 8;
          f32x4 f0 = *reinterpret_cast<const f32x4*>(ap);
          f32x4 f1 = *reinterpret_cast<const f32x4*>(ap + 4);
          w.x = pack2(f0[0], f0[1]); w.y = pack2(f0[2], f0[3]);
          w.z = pack2(f1[0], f1[1]); w.w = pack2(f1[2], f1[3]);
        }
      } else {
        const unsigned short* A = (const unsigned short*)Av;
        if (gr < M) w = *reinterpret_cast<const int4*>(A + (size_t)gr * K + k0 + c * 8);
      }
      *reinterpret_cast<int4*>(&lAt[row * 64 + ((c ^ (row & 7)) * 8)]) = w;
    }
    #pragma unroll
    for (int p = 0; p < (BN * 8) / 256; ++p) {
      int lin = p * 256 + t;
      int row = lin >> 3, c = lin & 7;
      int4 v = *reinterpret_cast<const int4*>(Bt + (size_t)(colBase + row) * K + k0 + c * 8);
      *reinterpret_cast<int4*>(&lBt[row * 64 + ((c ^ (row & 7)) * 8)]) = v;
    }
    __syncthreads();
    #pragma unroll
    for (int kk = 0; kk < 2; ++kk) {
      bf16x8 af[MR], bfr[NR];
      int cidx = kk * 4 + (lane >> 4);
      #pragma unroll
      for (int mi = 0; mi < MR; ++mi) {
        int row = wm * WTM + mi * 16 + (lane & 15);
        af[mi] = *reinterpret_cast<const bf16x8*>(&lAt[row * 64 + ((cidx ^ (row & 7)) * 8)]);
      }
      #pragma unroll
      for (int ni = 0; ni < NR; ++ni) {
        int row = wn * WTN + ni * 16 + (lane & 15);
        bfr[ni] = *reinterpret_cast<const bf16x8*>(&lBt[row * 64 + ((cidx ^ (row & 7)) * 8)]);
      }
      #pragma unroll
      for (int mi = 0; mi < MR; ++mi)
        #pragma unroll
        for (int ni = 0; ni < NR; ++ni)
          acc[mi][ni] = __builtin_amdgcn_mfma_f32_16x16x32_bf16(af[mi], bfr[ni], acc[mi][ni], 0, 0, 0);
    }
    __syncthreads();
  }
  #pragma unroll
  for (int mi = 0; mi < MR; ++mi)
    #pragma unroll
    for (int ni = 0; ni < NR; ++ni) {
      int col = colBase + wn * WTN + ni * 16 + (lane & 15);
      #pragma unroll
      for (int r = 0; r < 4; ++r) {
        int row = rowBase + wm * WTM + mi * 16 + (lane >> 4) * 4 + r;
        if (row < M) outp[(size_t)row * Ncol + col] = f2bf(acc[mi][ni][r]);
      }
    }
}

// ---------------- CSR build ----------------
__global__ __launch_bounds__(256) void hist_kernel(const int* __restrict__ dst, int* __restrict__ counts, int E) {
  int e = blockIdx.x * 256 + threadIdx.x;
  if (e < E) atomicAdd(&counts[dst[e]], 1);
}

__global__ __launch_bounds__(256) void scan_block(const int* __restrict__ in, int* __restrict__ out,
                                                  int* __restrict__ sums, int n) {
  int i = blockIdx.x * 256 + threadIdx.x;
  int lane = threadIdx.x & 63, wid = threadIdx.x >> 6;
  int v = (i < n) ? in[i] : 0;
  int s = v;
  #pragma unroll
  for (int d = 1; d < 64; d <<= 1) { int tt = __shfl_up(s, d); if (lane >= d) s += tt; }
  __shared__ int wsum[4];
  if (lane == 63) wsum[wid] = s;
  __syncthreads();
  int off = 0;
  for (int w = 0; w < wid; ++w) off += wsum[w];
  if (i < n) out[i] = off + s - v;  // exclusive
  if (threadIdx.x == 255) sums[blockIdx.x] = off + s;
}

__global__ __launch_bounds__(256) void scan_add(int* __restrict__ rs, const int* __restrict__ boffs,
                                                int* __restrict__ cursor, int n, int E) {
  int i = blockIdx.x * 256 + threadIdx.x;
  if (i < n) {
    int v = rs[i] + boffs[blockIdx.x];
    rs[i] = v;
    cursor[i] = v;
  }
  if (i == 0) rs[n] = E;
}

__global__ __launch_bounds__(256) void scatter_kernel(const int* __restrict__ src, const int* __restrict__ dst,
                                                      int* __restrict__ cursor, int* __restrict__ csr, int E) {
  int e = blockIdx.x * 256 + threadIdx.x;
  if (e < E) {
    int p = atomicAdd(&cursor[dst[e]], 1);
    csr[p] = src[e];
  }
}

// ---------------- edge aggregation helpers ----------------
template<int VEC>
__device__ __forceinline__ void load_row(const unsigned short* __restrict__ base,
                                         int s, int lane, float* v) {
  if constexpr (VEC == 4) {
    u16x4v r = *reinterpret_cast<const u16x4v*>(base + (size_t)s * 256 + lane * 4);
    #pragma unroll
    for (int j = 0; j < 4; ++j) v[j] = bf2f(r[j]);
  } else {
    v[0] = bf2f(base[(size_t)s * 64 + lane]);
  }
}

template<int VEC, int GROUP>
__device__ __forceinline__ float edge_score(const float* xv, const float* xrv, const float* attv) {
  float p = 0.f;
  #pragma unroll
  for (int j = 0; j < VEC; ++j) {
    float tv = xv[j] + xrv[j];
    tv = fmaxf(tv, 0.2f * tv);     // leaky_relu slope 0.2
    p = fmaf(tv, attv[j], p);
  }
  #pragma unroll
  for (int msk = 1; msk < GROUP; msk <<= 1) p += __shfl_xor(p, msk);
  return p;
}

// one wave per dst node (static; HW block scheduler balances as blocks retire);
// online softmax with deferred-max rescale (thr 8), 2-edge unroll for MLP.
template<int H, bool SELF, bool RELU>
__global__ __launch_bounds__(256) void edge_agg(
    const unsigned short* __restrict__ xl, const unsigned short* __restrict__ xr,
    const float* __restrict__ att, const float* __restrict__ bias,
    const int* __restrict__ rowstart, const int* __restrict__ csr,
    unsigned short* __restrict__ out, int N) {
  constexpr int F = H * 64;
  constexpr int VEC = F / 64;
  constexpr int GROUP = 64 / H;
  int wave = threadIdx.x >> 6, lane = threadIdx.x & 63;
  int node = blockIdx.x * 4 + wave;
  if (node >= N) return;

  float attv[VEC];
  #pragma unroll
  for (int j = 0; j < VEC; ++j) attv[j] = att[lane * VEC + j];

  float xrv[VEC];
  load_row<VEC>(xr, node, lane, xrv);

  int s0 = rowstart[node], s1 = rowstart[node + 1];
  int end = s1 + (SELF ? 1 : 0);

  float m = 0.f, l = 0.f;
  float acc[VEC];
  #pragma unroll
  for (int j = 0; j < VEC; ++j) acc[j] = 0.f;

  int i = s0;
  if (i < end) {           // first edge: m := its score, w == 1
    int s = (i < s1) ? csr[i] : node;
    float xv[VEC];
    load_row<VEC>(xl, s, lane, xv);
    m = edge_score<VEC, GROUP>(xv, xrv, attv);
    l = 1.f;
    #pragma unroll
    for (int j = 0; j < VEC; ++j) acc[j] = xv[j];
    ++i;
  }
  for (; i + 2 <= end; i += 2) {
    int sA = (i < s1) ? csr[i] : node;
    int sB = (i + 1 < s1) ? csr[i + 1] : node;
    float xa[VEC], xb[VEC];
    load_row<VEC>(xl, sA, lane, xa);
    load_row<VEC>(xl, sB, lane, xb);
    float pA = edge_score<VEC, GROUP>(xa, xrv, attv);
    float pB = edge_score<VEC, GROUP>(xb, xrv, attv);
    float mx = fmaxf(pA, pB);
    if (__any(mx > m + 8.f)) {          // rare rescale
      float mn = fmaxf(m, mx);
      float sc = __expf(m - mn);
      l *= sc;
      #pragma unroll
      for (int j = 0; j < VEC; ++j) acc[j] *= sc;
      m = mn;
    }
    float wA = __expf(pA - m), wB = __expf(pB - m);
    l += wA + wB;
    #pragma unroll
    for (int j = 0; j < VEC; ++j) acc[j] = fmaf(wA, xa[j], fmaf(wB, xb[j], acc[j]));
  }
  if (i < end) {
    int s = (i < s1) ? csr[i] : node;
    float xv[VEC];
    load_row<VEC>(xl, s, lane, xv);
    float p = edge_score<VEC, GROUP>(xv, xrv, attv);
    if (__any(p > m + 8.f)) {
      float mn = fmaxf(m, p);
      float sc = __expf(m - mn);
      l *= sc;
      #pragma unroll
      for (int j = 0; j < VEC; ++j) acc[j] *= sc;
      m = mn;
    }
    float w = __expf(p - m);
    l += w;
    #pragma unroll
    for (int j = 0; j < VEC; ++j) acc[j] = fmaf(w, xv[j], acc[j]);
  }

  float rec = 1.f / (l + 1e-16f);
  if constexpr (VEC == 4) {
    u16x4v w4;
    #pragma unroll
    for (int j = 0; j < 4; ++j) {
      float o = fmaf(acc[j], rec, bias[lane * 4 + j]);
      if (RELU) o = fmaxf(o, 0.f);
      w4[j] = f2bf(o);
    }
    *reinterpret_cast<u16x4v*>(out + (size_t)node * 256 + lane * 4) = w4;
  } else {
    float o = fmaf(acc[0], rec, bias[lane]);
    if (RELU) o = fmaxf(o, 0.f);
    out[(size_t)node * 64 + lane] = f2bf(o);
  }
}

// ---------------- global mean pool (atomic) ----------------
__global__ __launch_bounds__(256) void pool_kernel(const unsigned short* __restrict__ h,
                                                   const int* __restrict__ batch,
                                                   float* __restrict__ gsum, int* __restrict__ gcnt, int N) {
  int wave = threadIdx.x >> 6, lane = threadIdx.x & 63;
  int node = blockIdx.x * 4 + wave;
  if (node >= N) return;
  int b = batch[node];
  atomicAdd(&gsum[(size_t)b * 64 + lane], bf2f(h[(size_t)node * 64 + lane]));
  if (lane == 0) atomicAdd(&gcnt[b], 1);
}

// ---------------- MLP head + softmax: one wave per graph (all f32) ----------------
__global__ __launch_bounds__(256) void mlp_kernel(
    const float* __restrict__ gsum, const int* __restrict__ gcnt,
    const float* __restrict__ w1, const float* __restrict__ b1,
    const float* __restrict__ w2, const float* __restrict__ b2,
    const float* __restrict__ w3, const float* __restrict__ b3,
    float* __restrict__ out, int G) {
  int wave = threadIdx.x >> 6, lane = threadIdx.x & 63;
  int r = blockIdx.x * 4 + wave;
  bool ok = r < G;
  __shared__ float sh[4][64];
  float xv = 0.f;
  if (ok) {
    float cnt = fmaxf((float)gcnt[r], 1.0f);
    xv = gsum[(size_t)r * 64 + lane] / cnt;
  }
  sh[wave][lane] = xv;
  __syncthreads();
  float h1 = b1[lane];
  for (int k = 0; k < 64; ++k) h1 = fmaf(sh[wave][k], w1[k * 64 + lane], h1);
  h1 = fmaxf(h1, 0.f);
  __syncthreads();
  sh[wave][lane] = h1;
  __syncthreads();
  float h2 = b2[lane];
  for (int k = 0; k < 64; ++k) h2 = fmaf(sh[wave][k], w2[k * 64 + lane], h2);
  h2 = fmaxf(h2, 0.f);
  __syncthreads();
  sh[wave][lane] = h2;
  __syncthreads();
  float lg = -INFINITY;
  if (lane < 12) {
    lg = b3[lane];
    for (int k = 0; k < 64; ++k) lg = fmaf(sh[wave][k], w3[k * 12 + lane], lg);
  }
  float mx = lg;
  #pragma unroll
  for (int msk = 1; msk < 64; msk <<= 1) mx = fmaxf(mx, __shfl_xor(mx, msk));
  float ex = (lane < 12) ? __expf(lg - mx) : 0.f;
  float sm = ex;
  #pragma unroll
  for (int msk = 1; msk < 64; msk <<= 1) sm += __shfl_xor(sm, msk);
  if (ok && lane < 12) out[(size_t)r * 12 + lane] = ex / sm;
}

// ---------------- host ----------------
extern "C" void kernel_launch(void* const* d_in, const int* in_sizes, int n_in,
                              void* d_out, int out_size, void* d_ws, size_t ws_size,
                              hipStream_t stream) {
  const float* x    = (const float*)d_in[0];
  const int* edge   = (const int*)d_in[1];
  const int* batch  = (const int*)d_in[2];
  const float* W1l  = (const float*)d_in[3];
  const float* W1r  = (const float*)d_in[4];
  const float* a1   = (const float*)d_in[5];
  const float* b1   = (const float*)d_in[6];
  const float* W2l  = (const float*)d_in[7];
  const float* W2r  = (const float*)d_in[8];
  const float* a2   = (const float*)d_in[9];
  const float* b2   = (const float*)d_in[10];
  const float* W3l  = (const float*)d_in[11];
  const float* W3r  = (const float*)d_in[12];
  const float* a3   = (const float*)d_in[13];
  const float* b3   = (const float*)d_in[14];
  const float* lw1  = (const float*)d_in[15];
  const float* lb1  = (const float*)d_in[16];
  const float* lw2  = (const float*)d_in[17];
  const float* lb2  = (const float*)d_in[18];
  const float* lw3  = (const float*)d_in[19];
  const float* lb3  = (const float*)d_in[20];

  const int E = in_sizes[1] / 2;
  const int N = in_sizes[2];
  const int F0 = in_sizes[0] / N;   // 128
  const int G = out_size / 12;      // 512
  const int* src = edge;
  const int* dst = edge + E;

  // workspace carve (256B aligned)
  char* p = (char*)d_ws;
  auto alloc = [&](size_t bytes) { char* q = p; p += (bytes + 255) & ~(size_t)255; return q; };
  unsigned short* bufA = (unsigned short*)alloc((size_t)N * 256 * 2);
  unsigned short* bufB = (unsigned short*)alloc((size_t)N * 256 * 2);
  unsigned short* bufH = (unsigned short*)alloc((size_t)N * 256 * 2);
  unsigned short* Wt1L = (unsigned short*)alloc(128 * 256 * 2);
  unsigned short* Wt1R = (unsigned short*)alloc(128 * 256 * 2);
  unsigned short* Wt2L = (unsigned short*)alloc(256 * 256 * 2);
  unsigned short* Wt2R = (unsigned short*)alloc(256 * 256 * 2);
  unsigned short* Wt3L = (unsigned short*)alloc(256 * 64 * 2);
  unsigned short* Wt3R = (unsigned short*)alloc(256 * 64 * 2);
  int* counts   = (int*)alloc((size_t)N * 4);
  int* rowstart = (int*)alloc((size_t)(N + 1) * 4);
  int* cursor   = (int*)alloc((size_t)N * 4);
  int* bsums    = (int*)alloc(4096 * 4);
  int* boffs    = (int*)alloc(4096 * 4);
  int* dummy    = (int*)alloc(64 * 4);
  int* csr      = (int*)alloc((size_t)E * 4);
  float* gsum   = (float*)alloc((size_t)G * 64 * 4);  // contiguous with gcnt
  int* gcnt     = (int*)alloc((size_t)G * 4);

  // ---- CSR by dst (built once, reused by all convs) ----
  hipMemsetAsync(counts, 0, (size_t)N * 4, stream);
  hist_kernel<<<(E + 255) / 256, 256, 0, stream>>>(dst, counts, E);
  int nb = (N + 255) / 256;
  scan_block<<<nb, 256, 0, stream>>>(counts, rowstart, bsums, N);
  scan_block<<<1, 256, 0, stream>>>(bsums, boffs, dummy, nb);
  scan_add<<<nb, 256, 0, stream>>>(rowstart, boffs, cursor, N, E);
  scatter_kernel<<<(E + 255) / 256, 256, 0, stream>>>(src, dst, cursor, csr, E);

  // ---- all weight transposes in one launch ----
  {
    WPack wp;
    const float* ins[6] = {W1l, W1r, W2l, W2r, W3l, W3r};
    unsigned short* outs[6] = {Wt1L, Wt1R, Wt2L, Wt2R, Wt3L, Wt3R};
    int Ks[6] = {F0, F0, 256, 256, 256, 256};
    int Ns[6] = {256, 256, 256, 256, 64, 64};
    int acc0 = 0;
    for (int s = 0; s < 6; ++s) {
      wp.in[s] = ins[s]; wp.out[s] = outs[s]; wp.K[s] = Ks[s]; wp.Ncol[s] = Ns[s];
      wp.start[s] = acc0; acc0 += Ks[s] * Ns[s];
    }
    wp.start[6] = acc0;
    convert_all<<<(acc0 + 255) / 256, 256, 0, stream>>>(wp);
  }

  int gx = (N + 127) / 128;
  int ne = (N + 3) / 4;

  // ---- conv1: K=F0(128), Ncol=256, no self loops, relu; A = x (f32) ----
  gemm_dual<128, 2, 2, true><<<dim3(gx, 2, 2), 256, 0, stream>>>(x, Wt1L, Wt1R, bufA, bufB, N, F0, 256);
  edge_agg<4, false, true><<<ne, 256, 0, stream>>>(bufA, bufB, a1, b1, rowstart, csr, bufH, N);

  // ---- conv2: K=256, Ncol=256, self loops, relu; A = bufH (bf16) ----
  gemm_dual<128, 2, 2, false><<<dim3(gx, 2, 2), 256, 0, stream>>>(bufH, Wt2L, Wt2R, bufA, bufB, N, 256, 256);
  edge_agg<4, true, true><<<ne, 256, 0, stream>>>(bufA, bufB, a2, b2, rowstart, csr, bufH, N);

  // ---- conv3: K=256, Ncol=64, self loops, no relu; A = bufH (bf16) ----
  gemm_dual<64, 4, 1, false><<<dim3(gx, 1, 2), 256, 0, stream>>>(bufH, Wt3L, Wt3R, bufA, bufB, N, 256, 64);
  edge_agg<1, true, false><<<ne, 256, 0, stream>>>(bufA, bufB, a3, b3, rowstart, csr, bufH, N);

  // ---- global mean pool (gsum+gcnt zeroed in one memset; contiguous) ----
  hipMemsetAsync(gsum, 0, (size_t)G * 64 * 4 + (size_t)G * 4, stream);
  pool_kernel<<<ne, 256, 0, stream>>>(bufH, batch, gsum, gcnt, N);

  // ---- MLP head + softmax ----
  mlp_kernel<<<(G + 3) / 4, 256, 0, stream>>>(gsum, gcnt, lw1, lb1, lw2, lb2, lw3, lb3,
                                              (float*)d_out, G);
}